// Round 2
// baseline (520.598 us; speedup 1.0000x reference)
//
#include <hip/hip_runtime.h>
#include <math.h>

// Problem constants
#define BB 4
#define CC 64
#define C2 128
#define HH 128
#define WW 256
#define NN (BB*HH)          // 512 row-pairs
#define EPSBN 1e-5f

typedef _Float16 f16;
typedef _Float16 half8 __attribute__((ext_vector_type(8)));
typedef float f32x4 __attribute__((ext_vector_type(4)));

// ---------------------------------------------------------------------------
// K0: weight prep — rb_w fp32 [o][icg][3][3] -> f16 [g][mo][ks*32+ic]
// ---------------------------------------------------------------------------
__global__ __launch_bounds__(256) void k_wprep(
    const float* __restrict__ w1, const float* __restrict__ w2,
    f16* __restrict__ wp1, f16* __restrict__ wp2)
{
    int g = blockIdx.x; int which = blockIdx.y;
    const float* src = which ? w2 : w1;
    f16* dst = which ? wp2 : wp1;
    for (int p = threadIdx.x; p < 9216; p += 256) {
        int mo = p / 288; int kr = p - mo*288;
        int ks = kr >> 5; int ic = kr & 31;
        dst[g*9216 + p] = (f16)src[((g*32 + mo)*32 + ic)*9 + ks];
    }
}

// ---------------------------------------------------------------------------
// K1: fused 1x1 conv (64->64) + concat + batchnorm -> u (channel-last f16)
// ---------------------------------------------------------------------------
__global__ __launch_bounds__(256) void k_catbn_m(
    const float* __restrict__ x, const float* __restrict__ cw, const float* __restrict__ cb,
    const float* __restrict__ g, const float* __restrict__ bb_, const float* __restrict__ m,
    const float* __restrict__ v, f16* __restrict__ u)
{
    __shared__ f16 Xl[256][72];   // [px][ic]
    __shared__ f16 Wl[64][72];    // [oc][ic]
    __shared__ float sS[64], sT[64], sS2[64], sT2[64];
    int n = blockIdx.x; int b = n >> 7; int h = n & 127; int t = threadIdx.x;
    for (int p = t; p < 2048; p += 256) {
        int idx = p * 2; int o = idx >> 6, i = idx & 63;
        union { f16 h[2]; unsigned int u1; } pr;
        pr.h[0] = (f16)cw[idx]; pr.h[1] = (f16)cw[idx + 1];
        *(unsigned int*)&Wl[o][i] = pr.u1;
    }
    if (t < 64) {
        float inv = rsqrtf(v[t] + EPSBN); float s = g[t] * inv;
        sS[t] = s; sT[t] = bb_[t] + s * (cb[t] - m[t]);
        float inv2 = rsqrtf(v[t + 64] + EPSBN); float s2 = g[t + 64] * inv2;
        sS2[t] = s2; sT2[t] = bb_[t + 64] - s2 * m[t + 64];
    }
    __syncthreads();
    f16* up = u + ((size_t)(n*256 + t)) * 128;
    for (int c8 = 0; c8 < 8; ++c8) {
        float xv8[8];
#pragma unroll
        for (int j = 0; j < 8; ++j)
            xv8[j] = x[(((b*64 + c8*8 + j)*128 + h) << 8) + t];
        union { f16 h[8]; uint4 v4; } pk;
#pragma unroll
        for (int j = 0; j < 8; ++j) {
            int c = c8*8 + j;
            pk.h[j] = (f16)(sS2[c]*xv8[j] + sT2[c]);
        }
        *(uint4*)(up + 64 + c8*8) = pk.v4;
#pragma unroll
        for (int j2 = 0; j2 < 4; ++j2) {
            union { f16 h[2]; unsigned int u1; } q;
            q.h[0] = (f16)xv8[j2*2]; q.h[1] = (f16)xv8[j2*2 + 1];
            *(unsigned int*)&Xl[t][c8*8 + j2*2] = q.u1;
        }
    }
    __syncthreads();
    int lane = t & 63, wv = t >> 6;
    int m16 = lane & 15, quad = lane >> 4;
    half8 af[4][2], bf[4][2];
#pragma unroll
    for (int mt = 0; mt < 4; ++mt)
#pragma unroll
        for (int kk = 0; kk < 2; ++kk)
            af[mt][kk] = *(const half8*)&Wl[mt*16 + m16][kk*32 + quad*8];
#pragma unroll
    for (int nt = 0; nt < 4; ++nt)
#pragma unroll
        for (int kk = 0; kk < 2; ++kk)
            bf[nt][kk] = *(const half8*)&Xl[wv*64 + nt*16 + m16][kk*32 + quad*8];
    f32x4 acc[4][4] = {};
#pragma unroll
    for (int mt = 0; mt < 4; ++mt)
#pragma unroll
        for (int nt = 0; nt < 4; ++nt) {
            acc[mt][nt] = __builtin_amdgcn_mfma_f32_16x16x32_f16(af[mt][0], bf[nt][0], acc[mt][nt], 0, 0, 0);
            acc[mt][nt] = __builtin_amdgcn_mfma_f32_16x16x32_f16(af[mt][1], bf[nt][1], acc[mt][nt], 0, 0, 0);
        }
#pragma unroll
    for (int mt = 0; mt < 4; ++mt) {
        int ocb = mt*16 + quad*4;
        float s4[4], t4[4];
        *(float4*)s4 = *(const float4*)&sS[ocb];
        *(float4*)t4 = *(const float4*)&sT[ocb];
#pragma unroll
        for (int nt = 0; nt < 4; ++nt) {
            int px = wv*64 + nt*16 + m16;
            union { f16 h[4]; uint2 u2; } ov;
#pragma unroll
            for (int r = 0; r < 4; ++r)
                ov.h[r] = (f16)(s4[r]*acc[mt][nt][r] + t4[r]);
            *(uint2*)(u + ((size_t)(n*256 + px))*128 + ocb) = ov.u2;
        }
    }
}

// ---------------------------------------------------------------------------
// K2/K3: grouped 3x3 conv, implicit-GEMM f16 MFMA, 4 output rows per block.
// ---------------------------------------------------------------------------
template<bool LEAKY, bool RES>
__global__ __launch_bounds__(256, 2) void k_conv3r(
    const f16* __restrict__ in, const f16* __restrict__ wp,
    const float* __restrict__ bias, const f16* __restrict__ res,
    f16* __restrict__ out)
{
    __shared__ f16 Xl[6*130*40];  // [row][px][ic] px-stride 40
    int b = blockIdx.x >> 5; int h0 = (blockIdx.x & 31) * 4;
    int g = blockIdx.y; int w0 = blockIdx.z * 128;
    int t = threadIdx.x;
    int lane = t & 63, wv = t >> 6;
    int m16 = lane & 15, quad = lane >> 4;
    const f16* wg = wp + g*9216;
    half8 af[2][9];
#pragma unroll
    for (int mt = 0; mt < 2; ++mt)
#pragma unroll
        for (int ks = 0; ks < 9; ++ks)
            af[mt][ks] = *(const half8*)(wg + (mt*16 + m16)*288 + ks*32 + quad*8);
    float bo[2][4];
#pragma unroll
    for (int mt = 0; mt < 2; ++mt)
#pragma unroll
        for (int r = 0; r < 4; ++r)
            bo[mt][r] = bias[g*32 + mt*16 + quad*4 + r];
    for (int idx = t; idx < 3120; idx += 256) {
        int r = idx / 520; int rem = idx - r*520; int p = rem >> 2; int q = rem & 3;
        int hr = h0 + r - 1; int wg2 = w0 + p - 1;
        uint4 val = make_uint4(0,0,0,0);
        if ((unsigned)wg2 < 256u && (unsigned)hr < 128u)
            val = *(const uint4*)(in + ((size_t)((b*128 + hr)*256 + wg2))*128 + g*32 + q*8);
        *(uint4*)&Xl[(r*130 + p)*40 + q*8] = val;
    }
    __syncthreads();
    int px0 = wv*32 + m16;
#pragma unroll
    for (int rr = 0; rr < 4; ++rr) {
        f32x4 acc[2][2] = {};
#pragma unroll
        for (int ks = 0; ks < 9; ++ks) {
            int ky = ks / 3, kx = ks - ky*3;
            half8 bf0 = *(const half8*)&Xl[((rr + ky)*130 + px0 + kx)*40 + quad*8];
            half8 bf1 = *(const half8*)&Xl[((rr + ky)*130 + px0 + 16 + kx)*40 + quad*8];
            acc[0][0] = __builtin_amdgcn_mfma_f32_16x16x32_f16(af[0][ks], bf0, acc[0][0], 0, 0, 0);
            acc[0][1] = __builtin_amdgcn_mfma_f32_16x16x32_f16(af[0][ks], bf1, acc[0][1], 0, 0, 0);
            acc[1][0] = __builtin_amdgcn_mfma_f32_16x16x32_f16(af[1][ks], bf0, acc[1][0], 0, 0, 0);
            acc[1][1] = __builtin_amdgcn_mfma_f32_16x16x32_f16(af[1][ks], bf1, acc[1][1], 0, 0, 0);
        }
        int h = h0 + rr;
#pragma unroll
        for (int mt = 0; mt < 2; ++mt)
#pragma unroll
            for (int nt = 0; nt < 2; ++nt) {
                int px = w0 + wv*32 + nt*16 + m16;
                int oc = g*32 + mt*16 + quad*4;
                size_t off = ((size_t)((b*128 + h)*256 + px))*128 + oc;
                float rv4[4] = {0.f, 0.f, 0.f, 0.f};
                if (RES) {
                    union { f16 h[4]; uint2 v2; } rrd;
                    rrd.v2 = *(const uint2*)(res + off);
#pragma unroll
                    for (int r = 0; r < 4; ++r) rv4[r] = (float)rrd.h[r];
                }
                union { f16 h[4]; uint2 v2; } ov;
#pragma unroll
                for (int r = 0; r < 4; ++r) {
                    float y = acc[mt][nt][r] + bo[mt][r];
                    if (LEAKY) y = y > 0.f ? y : 0.1f*y;
                    if (RES) y += rv4[r];
                    ov.h[r] = (f16)y;
                }
                *(uint2*)(out + off) = ov.v2;
            }
    }
}

// ---------------------------------------------------------------------------
// K4: grouped 1x1 conv (128->64, groups=2) + row-mean subtraction, MFMA f16.
// ---------------------------------------------------------------------------
__global__ __launch_bounds__(256, 2) void k_conv1x1m(
    const f16* __restrict__ in, const float* __restrict__ wgt,
    f16* __restrict__ outq)
{
    __shared__ f16 Xl[256][72];       // one group's 64 ic (+8 pad)
    __shared__ f16 Wl[64][72];        // all 64 oc, within-group ic
    __shared__ float partial[4][64];  // per-wave px-sums per oc
    __shared__ float meanS[64];
    int n = blockIdx.x; int t = threadIdx.x;
    int lane = t & 63, wv = t >> 6;
    int m16 = lane & 15, quad = lane >> 4;
    for (int p = t; p < 2048; p += 256) {
        int idx = p * 2; int o = idx >> 6, i = idx & 63;
        union { f16 h[2]; unsigned int u1; } pr;
        pr.h[0] = (f16)wgt[idx]; pr.h[1] = (f16)wgt[idx + 1];
        *(unsigned int*)&Wl[o][i] = pr.u1;
    }
    f32x4 acc[4][4] = {};             // [oc tile 0..3][px tile 0..3]
    const f16* rp = in + ((size_t)n*256 + t)*128;
    for (int g = 0; g < 2; ++g) {
#pragma unroll
        for (int i8 = 0; i8 < 8; ++i8)
            *(uint4*)&Xl[t][i8*8] = *(const uint4*)(rp + g*64 + i8*8);
        __syncthreads();
        half8 af[2][2], bf[4][2];
#pragma unroll
        for (int ml = 0; ml < 2; ++ml)
#pragma unroll
            for (int kk = 0; kk < 2; ++kk)
                af[ml][kk] = *(const half8*)&Wl[g*32 + ml*16 + m16][kk*32 + quad*8];
#pragma unroll
        for (int nt = 0; nt < 4; ++nt)
#pragma unroll
            for (int kk = 0; kk < 2; ++kk)
                bf[nt][kk] = *(const half8*)&Xl[wv*64 + nt*16 + m16][kk*32 + quad*8];
#pragma unroll
        for (int ml = 0; ml < 2; ++ml)
#pragma unroll
            for (int nt = 0; nt < 4; ++nt) {
                int mt = g*2 + ml;
                acc[mt][nt] = __builtin_amdgcn_mfma_f32_16x16x32_f16(af[ml][0], bf[nt][0], acc[mt][nt], 0, 0, 0);
                acc[mt][nt] = __builtin_amdgcn_mfma_f32_16x16x32_f16(af[ml][1], bf[nt][1], acc[mt][nt], 0, 0, 0);
            }
        __syncthreads();
    }
#pragma unroll
    for (int mt = 0; mt < 4; ++mt)
#pragma unroll
        for (int r = 0; r < 4; ++r) {
            float s = acc[mt][0][r] + acc[mt][1][r] + acc[mt][2][r] + acc[mt][3][r];
            s += __shfl_xor(s, 1); s += __shfl_xor(s, 2);
            s += __shfl_xor(s, 4); s += __shfl_xor(s, 8);
            if (m16 == 0) partial[wv][mt*16 + quad*4 + r] = s;
        }
    __syncthreads();
    if (t < 64)
        meanS[t] = (partial[0][t] + partial[1][t] + partial[2][t] + partial[3][t]) * (1.0f/256.0f);
    __syncthreads();
    f16* qp = outq + ((size_t)n*256)*64;
#pragma unroll
    for (int mt = 0; mt < 4; ++mt) {
        int ocb = mt*16 + quad*4;
        float m4[4]; *(float4*)m4 = *(const float4*)&meanS[ocb];
#pragma unroll
        for (int nt = 0; nt < 4; ++nt) {
            int px = wv*64 + nt*16 + m16;
            union { f16 h[4]; uint2 u2; } ov;
#pragma unroll
            for (int r = 0; r < 4; ++r)
                ov.h[r] = (f16)(acc[mt][nt][r] - m4[r]);
            *(uint2*)(qp + (size_t)px*64 + ocb) = ov.u2;
        }
    }
}

// ---------------------------------------------------------------------------
// K5: fused attention tail.  One block per n (512 thr = 8 waves).
// S = A·B^T computed via MFMA into LDS (f16, XOR-swizzled); row/col softmax
// stats from LDS; then per-32-col chunk: P staging (exp), window-V, and
// PV MFMA — identical math to the old k_score/k_stats/k_out chain but with
// zero HBM traffic for S.  Called twice with A/B and x roles swapped
// (S' = K·Q^T = S^T makes the two calls symmetric).
// LDS: S 128K + Pl 20.3K + Xl 5K + stats 4K + scr 2K = 159.3 KiB.
// ---------------------------------------------------------------------------
__global__ __launch_bounds__(512, 1) void k_attn(
    const f16* __restrict__ Aq, const f16* __restrict__ Bk,
    const float* __restrict__ xB, const float* __restrict__ xP,
    float* __restrict__ outp)
{
    __shared__ f16 Sl[65536];         // byte = row*512 + ((col*2) ^ ((row&7)<<4))
    __shared__ f16 Pl[260][40];       // P chunk, rows offset +2 (window pad)
    __shared__ f16 Xl[64][40];        // xB chunk [c][j]
    __shared__ float rmS[256], riS[256], cmS[256], ciS[256];
    __shared__ float scr[2][256];
    int n = blockIdx.x; int b = n >> 7; int h = n & 127;
    int t = threadIdx.x;
    int lane = t & 63, wv = t >> 6;        // wv 0..7
    int m16 = lane & 15, quad = lane >> 4;
    int W = wv * 32;                       // this wave's 32 S-rows / PV-rows

    // ---- phase 1: S = A·B^T -> LDS (f16, swizzled) ----
    const f16* ag = Aq + (size_t)n*16384;
    const f16* bg = Bk + (size_t)n*16384;
    half8 af1[2][2];
#pragma unroll
    for (int mt = 0; mt < 2; ++mt)
#pragma unroll
        for (int kk = 0; kk < 2; ++kk)
            af1[mt][kk] = *(const half8*)(ag + (size_t)(W + mt*16 + m16)*64 + kk*32 + quad*8);
    for (int jc = 0; jc < 256; jc += 64) {
        half8 bf1[4][2];
#pragma unroll
        for (int nt = 0; nt < 4; ++nt)
#pragma unroll
            for (int kk = 0; kk < 2; ++kk)
                bf1[nt][kk] = *(const half8*)(bg + (size_t)(jc + nt*16 + m16)*64 + kk*32 + quad*8);
        f32x4 acc1[2][4] = {};
#pragma unroll
        for (int mt = 0; mt < 2; ++mt)
#pragma unroll
            for (int nt = 0; nt < 4; ++nt) {
                acc1[mt][nt] = __builtin_amdgcn_mfma_f32_16x16x32_f16(af1[mt][0], bf1[nt][0], acc1[mt][nt], 0, 0, 0);
                acc1[mt][nt] = __builtin_amdgcn_mfma_f32_16x16x32_f16(af1[mt][1], bf1[nt][1], acc1[mt][nt], 0, 0, 0);
            }
#pragma unroll
        for (int mt = 0; mt < 2; ++mt)
#pragma unroll
            for (int nt = 0; nt < 4; ++nt)
#pragma unroll
                for (int r = 0; r < 4; ++r) {
                    int row = W + mt*16 + quad*4 + r;
                    int col = jc + nt*16 + m16;
                    int byte = (row << 9) + ((col*2) ^ ((row & 7) << 4));
                    *(f16*)((char*)Sl + byte) = (f16)acc1[mt][nt][r];
                }
    }
    __syncthreads();

    // ---- phase 2: softmax stats (rows: t<256, cols: t>=256) ----
    if (t < 256) {
        int r = t; int xo = (r & 7) << 4;
        const char* base = (const char*)Sl + (r << 9);
        float m = -1e30f;
#pragma unroll 4
        for (int g = 0; g < 32; ++g) {
            half8 v8 = *(const half8*)(base + ((g*16) ^ xo));
#pragma unroll
            for (int e = 0; e < 8; ++e) m = fmaxf(m, (float)v8[e]);
        }
        float s = 0.f;
#pragma unroll 4
        for (int g = 0; g < 32; ++g) {
            half8 v8 = *(const half8*)(base + ((g*16) ^ xo));
#pragma unroll
            for (int e = 0; e < 8; ++e) s += __expf((float)v8[e] - m);
        }
        rmS[r] = m; riS[r] = 1.0f/s;
    } else {
        int c = t - 256; int c2 = c*2;
        const char* base = (const char*)Sl;
        float m = -1e30f;
#pragma unroll 8
        for (int row = 0; row < 256; ++row) {
            f16 v = *(const f16*)(base + (row << 9) + (c2 ^ ((row & 7) << 4)));
            m = fmaxf(m, (float)v);
        }
        float s = 0.f;
#pragma unroll 8
        for (int row = 0; row < 256; ++row) {
            f16 v = *(const f16*)(base + (row << 9) + (c2 ^ ((row & 7) << 4)));
            s += __expf((float)v - m);
        }
        cmS[c] = m; ciS[c] = 1.0f/s;
    }
    // zero window-pad rows of Pl (rows 0,1 and 258,259; 160 B each pair)
    if (t < 10)       *(uint4*)((char*)&Pl[0][0]   + t*16)      = make_uint4(0,0,0,0);
    else if (t < 20)  *(uint4*)((char*)&Pl[258][0] + (t-10)*16) = make_uint4(0,0,0,0);
    __syncthreads();

    // ---- phase 3: per-chunk P staging + window-V + PV MFMA ----
    int r = t & 255, hc = t >> 8;          // thread owns (row r, 16-col half hc)
    int cbase = hc * 16;
    float rm = rmS[r], ri = riS[r];
    int xc = t >> 3, xj = (t & 7) * 4;     // Xl staging role: channel xc, 4 cols
    const float* xg = xB + ((size_t)(b*64 + xc)*128 + h)*256;
    f32x4 acc[2][4] = {};
    float vacc = 0.f;
    const char* sb = (const char*)Sl + (r << 9);
    int xo = (r & 7) << 4;
    for (int kc = 0; kc < 256; kc += 32) {
        // stage P chunk (keep raw S values for Bv)
        float sraw[16];
        {
            half8 v0 = *(const half8*)(sb + ((((kc + cbase)*2))      ^ xo));
            half8 v1 = *(const half8*)(sb + ((((kc + cbase)*2) + 16) ^ xo));
            half8 p0, p1;
#pragma unroll
            for (int e = 0; e < 8; ++e) {
                sraw[e] = (float)v0[e];
                p0[e] = (f16)(__expf(sraw[e] - rm) * ri);
            }
#pragma unroll
            for (int e = 0; e < 8; ++e) {
                sraw[8 + e] = (float)v1[e];
                p1[e] = (f16)(__expf(sraw[8 + e] - rm) * ri);
            }
            char* pb = (char*)&Pl[r + 2][cbase];
            *(half8*)pb = p0; *(half8*)(pb + 16) = p1;
        }
        // stage Xl chunk (64 ch x 32 j)
        {
            float4 x4 = *(const float4*)(xg + kc + xj);
            union { f16 h[4]; uint2 v2; } px;
            px.h[0] = (f16)x4.x; px.h[1] = (f16)x4.y;
            px.h[2] = (f16)x4.z; px.h[3] = (f16)x4.w;
            *(uint2*)&Xl[xc][xj] = px.v2;
        }
        __syncthreads();
        // window + V partial
#pragma unroll
        for (int j8 = 0; j8 < 2; ++j8) {
            const char* wb = (const char*)&Pl[r][cbase + j8*8];
            half8 w0 = *(const half8*)(wb);
            half8 w1 = *(const half8*)(wb + 80);
            half8 w2 = *(const half8*)(wb + 160);
            half8 w3 = *(const half8*)(wb + 240);
            half8 w4 = *(const half8*)(wb + 320);
            half8 win = w0 + w1 + w2 + w3 + w4;
#pragma unroll
            for (int e = 0; e < 8; ++e) {
                int j = kc + cbase + j8*8 + e;
                float Bv = __expf(sraw[j8*8 + e] - cmS[j]) * ciS[j];
                vacc = fmaf((float)win[e], Bv, vacc);
            }
        }
        // PV MFMA: 2 row-tiles x 4 ch-tiles, k = this 32-col chunk
        half8 pa[2], xb_[4];
#pragma unroll
        for (int mt = 0; mt < 2; ++mt)
            pa[mt] = *(const half8*)((const char*)&Pl[W + mt*16 + m16 + 2][0] + quad*16);
#pragma unroll
        for (int nt = 0; nt < 4; ++nt)
            xb_[nt] = *(const half8*)((const char*)&Xl[nt*16 + m16][0] + quad*16);
#pragma unroll
        for (int mt = 0; mt < 2; ++mt)
#pragma unroll
            for (int nt = 0; nt < 4; ++nt)
                acc[mt][nt] = __builtin_amdgcn_mfma_f32_16x16x32_f16(pa[mt], xb_[nt], acc[mt][nt], 0, 0, 0);
        __syncthreads();
    }
    // ---- V merge + epilogue ----
    scr[hc][r] = vacc;
    __syncthreads();
    if (t < 256) rmS[t] = scr[0][t] + scr[1][t];   // reuse rmS as V[px]
    __syncthreads();
#pragma unroll
    for (int mt = 0; mt < 2; ++mt) {
        int i0 = W + mt*16 + quad*4;
        float v4[4];
        *(float4*)v4 = *(const float4*)&rmS[i0];
        float tv[4];
#pragma unroll
        for (int rr = 0; rr < 4; ++rr) tv[rr] = tanhf(5.f*v4[rr]);
#pragma unroll
        for (int nt = 0; nt < 4; ++nt) {
            int c = nt*16 + m16;
            size_t base = (((size_t)(b*64 + c)*128 + h) << 8) + i0;
            float xp4[4]; *(float4*)xp4 = *(const float4*)&xP[base];
            float o4[4];
#pragma unroll
            for (int rr = 0; rr < 4; ++rr)
                o4[rr] = xp4[rr]*(1.f - tv[rr]) + acc[mt][nt][rr]*tv[rr];
            *(float4*)&outp[base] = *(float4*)o4;
        }
    }
}

// ---------------------------------------------------------------------------
extern "C" void kernel_launch(void* const* d_in, const int* in_sizes, int n_in,
                              void* d_out, int out_size, void* d_ws, size_t ws_size,
                              hipStream_t stream)
{
    const float* x_left  = (const float*)d_in[0];
    const float* x_right = (const float*)d_in[1];
    const float* conv1_w = (const float*)d_in[2];
    const float* conv1_b = (const float*)d_in[3];
    const float* conv2_w = (const float*)d_in[4];
    const float* conv2_b = (const float*)d_in[5];
    const float* bn_g    = (const float*)d_in[6];
    const float* bn_b    = (const float*)d_in[7];
    const float* bn_m    = (const float*)d_in[8];
    const float* bn_v    = (const float*)d_in[9];
    const float* rb_w1   = (const float*)d_in[10];
    const float* rb_b1   = (const float*)d_in[11];
    const float* rb_w2   = (const float*)d_in[12];
    const float* rb_b2   = (const float*)d_in[13];
    const float* bq_w    = (const float*)d_in[14];
    const float* bs_w    = (const float*)d_in[16];

    f16* W16 = (f16*)d_ws;
    f16* u  = W16;                       // 16,777,216 els
    f16* y1 = W16 + 16777216;            // 16,777,216
    f16* r  = W16 + 33554432;            // 16,777,216
    f16* Qh = W16 + 67108864;            //  8,388,608
    f16* Kh = W16 + 75497472;            //  8,388,608
    f16* Wp1 = W16 + 84934656;           // 36,864 els (prepped rb_w1)
    f16* Wp2 = W16 + 84971520;           // 36,864 els (prepped rb_w2)

    float* out_left  = (float*)d_out;
    float* out_right = (float*)d_out + 8388608;

    // ---- weight prep (once per launch) ----
    k_wprep<<<dim3(4, 2), 256, 0, stream>>>(rb_w1, rb_w2, Wp1, Wp2);

    // ---- left branch -> Q ----
    k_catbn_m<<<NN, 256, 0, stream>>>(x_left, conv1_w, conv1_b, bn_g, bn_b, bn_m, bn_v, u);
    k_conv3r<true,  false><<<dim3(128, 4, 2), 256, 0, stream>>>(u, Wp1, rb_b1, nullptr, y1);
    k_conv3r<false, true ><<<dim3(128, 4, 2), 256, 0, stream>>>(y1, Wp2, rb_b2, u, r);
    k_conv1x1m<<<NN, 256, 0, stream>>>(r, bq_w, Qh);

    // ---- right branch -> K ----
    k_catbn_m<<<NN, 256, 0, stream>>>(x_right, conv2_w, conv2_b, bn_g, bn_b, bn_m, bn_v, u);
    k_conv3r<true,  false><<<dim3(128, 4, 2), 256, 0, stream>>>(u, Wp1, rb_b1, nullptr, y1);
    k_conv3r<false, true ><<<dim3(128, 4, 2), 256, 0, stream>>>(y1, Wp2, rb_b2, u, r);
    k_conv1x1m<<<NN, 256, 0, stream>>>(r, bs_w, Kh);

    // ---- fused attention tail (S in LDS; two symmetric calls) ----
    k_attn<<<NN, 512, 0, stream>>>(Qh, Kh, x_right, x_left,  out_left);
    k_attn<<<NN, 512, 0, stream>>>(Kh, Qh, x_left,  x_right, out_right);
}

// Round 3
// 438.276 us; speedup vs baseline: 1.1878x; 1.1878x over previous
//
#include <hip/hip_runtime.h>
#include <math.h>

// Problem constants
#define BB 4
#define CC 64
#define C2 128
#define HH 128
#define WW 256
#define NN (BB*HH)          // 512 row-pairs
#define EPSBN 1e-5f

typedef _Float16 f16;
typedef _Float16 half8 __attribute__((ext_vector_type(8)));
typedef float f32x4 __attribute__((ext_vector_type(4)));

// ---------------------------------------------------------------------------
// K0: weight prep — rb_w fp32 [o][icg][3][3] -> f16 [g][mo][ks*32+ic]
// ---------------------------------------------------------------------------
__global__ __launch_bounds__(256) void k_wprep(
    const float* __restrict__ w1, const float* __restrict__ w2,
    f16* __restrict__ wp1, f16* __restrict__ wp2)
{
    int g = blockIdx.x; int which = blockIdx.y;
    const float* src = which ? w2 : w1;
    f16* dst = which ? wp2 : wp1;
    for (int p = threadIdx.x; p < 9216; p += 256) {
        int mo = p / 288; int kr = p - mo*288;
        int ks = kr >> 5; int ic = kr & 31;
        dst[g*9216 + p] = (f16)src[((g*32 + mo)*32 + ic)*9 + ks];
    }
}

// ---------------------------------------------------------------------------
// K1: fused 1x1 conv (64->64) + concat + batchnorm -> u (channel-last f16)
// ---------------------------------------------------------------------------
__global__ __launch_bounds__(256) void k_catbn_m(
    const float* __restrict__ x, const float* __restrict__ cw, const float* __restrict__ cb,
    const float* __restrict__ g, const float* __restrict__ bb_, const float* __restrict__ m,
    const float* __restrict__ v, f16* __restrict__ u)
{
    __shared__ f16 Xl[256][72];   // [px][ic]
    __shared__ f16 Wl[64][72];    // [oc][ic]
    __shared__ float sS[64], sT[64], sS2[64], sT2[64];
    int n = blockIdx.x; int b = n >> 7; int h = n & 127; int t = threadIdx.x;
    for (int p = t; p < 2048; p += 256) {
        int idx = p * 2; int o = idx >> 6, i = idx & 63;
        union { f16 h[2]; unsigned int u1; } pr;
        pr.h[0] = (f16)cw[idx]; pr.h[1] = (f16)cw[idx + 1];
        *(unsigned int*)&Wl[o][i] = pr.u1;
    }
    if (t < 64) {
        float inv = rsqrtf(v[t] + EPSBN); float s = g[t] * inv;
        sS[t] = s; sT[t] = bb_[t] + s * (cb[t] - m[t]);
        float inv2 = rsqrtf(v[t + 64] + EPSBN); float s2 = g[t + 64] * inv2;
        sS2[t] = s2; sT2[t] = bb_[t + 64] - s2 * m[t + 64];
    }
    __syncthreads();
    f16* up = u + ((size_t)(n*256 + t)) * 128;
    for (int c8 = 0; c8 < 8; ++c8) {
        float xv8[8];
#pragma unroll
        for (int j = 0; j < 8; ++j)
            xv8[j] = x[(((b*64 + c8*8 + j)*128 + h) << 8) + t];
        union { f16 h[8]; uint4 v4; } pk;
#pragma unroll
        for (int j = 0; j < 8; ++j) {
            int c = c8*8 + j;
            pk.h[j] = (f16)(sS2[c]*xv8[j] + sT2[c]);
        }
        *(uint4*)(up + 64 + c8*8) = pk.v4;
#pragma unroll
        for (int j2 = 0; j2 < 4; ++j2) {
            union { f16 h[2]; unsigned int u1; } q;
            q.h[0] = (f16)xv8[j2*2]; q.h[1] = (f16)xv8[j2*2 + 1];
            *(unsigned int*)&Xl[t][c8*8 + j2*2] = q.u1;
        }
    }
    __syncthreads();
    int lane = t & 63, wv = t >> 6;
    int m16 = lane & 15, quad = lane >> 4;
    half8 af[4][2], bf[4][2];
#pragma unroll
    for (int mt = 0; mt < 4; ++mt)
#pragma unroll
        for (int kk = 0; kk < 2; ++kk)
            af[mt][kk] = *(const half8*)&Wl[mt*16 + m16][kk*32 + quad*8];
#pragma unroll
    for (int nt = 0; nt < 4; ++nt)
#pragma unroll
        for (int kk = 0; kk < 2; ++kk)
            bf[nt][kk] = *(const half8*)&Xl[wv*64 + nt*16 + m16][kk*32 + quad*8];
    f32x4 acc[4][4] = {};
#pragma unroll
    for (int mt = 0; mt < 4; ++mt)
#pragma unroll
        for (int nt = 0; nt < 4; ++nt) {
            acc[mt][nt] = __builtin_amdgcn_mfma_f32_16x16x32_f16(af[mt][0], bf[nt][0], acc[mt][nt], 0, 0, 0);
            acc[mt][nt] = __builtin_amdgcn_mfma_f32_16x16x32_f16(af[mt][1], bf[nt][1], acc[mt][nt], 0, 0, 0);
        }
#pragma unroll
    for (int mt = 0; mt < 4; ++mt) {
        int ocb = mt*16 + quad*4;
        float s4[4], t4[4];
        *(float4*)s4 = *(const float4*)&sS[ocb];
        *(float4*)t4 = *(const float4*)&sT[ocb];
#pragma unroll
        for (int nt = 0; nt < 4; ++nt) {
            int px = wv*64 + nt*16 + m16;
            union { f16 h[4]; uint2 u2; } ov;
#pragma unroll
            for (int r = 0; r < 4; ++r)
                ov.h[r] = (f16)(s4[r]*acc[mt][nt][r] + t4[r]);
            *(uint2*)(u + ((size_t)(n*256 + px))*128 + ocb) = ov.u2;
        }
    }
}

// ---------------------------------------------------------------------------
// K2/K3: grouped 3x3 conv, implicit-GEMM f16 MFMA, 4 output rows per block.
// ---------------------------------------------------------------------------
template<bool LEAKY, bool RES>
__global__ __launch_bounds__(256, 2) void k_conv3r(
    const f16* __restrict__ in, const f16* __restrict__ wp,
    const float* __restrict__ bias, const f16* __restrict__ res,
    f16* __restrict__ out)
{
    __shared__ f16 Xl[6*130*40];  // [row][px][ic] px-stride 40
    int b = blockIdx.x >> 5; int h0 = (blockIdx.x & 31) * 4;
    int g = blockIdx.y; int w0 = blockIdx.z * 128;
    int t = threadIdx.x;
    int lane = t & 63, wv = t >> 6;
    int m16 = lane & 15, quad = lane >> 4;
    const f16* wg = wp + g*9216;
    half8 af[2][9];
#pragma unroll
    for (int mt = 0; mt < 2; ++mt)
#pragma unroll
        for (int ks = 0; ks < 9; ++ks)
            af[mt][ks] = *(const half8*)(wg + (mt*16 + m16)*288 + ks*32 + quad*8);
    float bo[2][4];
#pragma unroll
    for (int mt = 0; mt < 2; ++mt)
#pragma unroll
        for (int r = 0; r < 4; ++r)
            bo[mt][r] = bias[g*32 + mt*16 + quad*4 + r];
    for (int idx = t; idx < 3120; idx += 256) {
        int r = idx / 520; int rem = idx - r*520; int p = rem >> 2; int q = rem & 3;
        int hr = h0 + r - 1; int wg2 = w0 + p - 1;
        uint4 val = make_uint4(0,0,0,0);
        if ((unsigned)wg2 < 256u && (unsigned)hr < 128u)
            val = *(const uint4*)(in + ((size_t)((b*128 + hr)*256 + wg2))*128 + g*32 + q*8);
        *(uint4*)&Xl[(r*130 + p)*40 + q*8] = val;
    }
    __syncthreads();
    int px0 = wv*32 + m16;
#pragma unroll
    for (int rr = 0; rr < 4; ++rr) {
        f32x4 acc[2][2] = {};
#pragma unroll
        for (int ks = 0; ks < 9; ++ks) {
            int ky = ks / 3, kx = ks - ky*3;
            half8 bf0 = *(const half8*)&Xl[((rr + ky)*130 + px0 + kx)*40 + quad*8];
            half8 bf1 = *(const half8*)&Xl[((rr + ky)*130 + px0 + 16 + kx)*40 + quad*8];
            acc[0][0] = __builtin_amdgcn_mfma_f32_16x16x32_f16(af[0][ks], bf0, acc[0][0], 0, 0, 0);
            acc[0][1] = __builtin_amdgcn_mfma_f32_16x16x32_f16(af[0][ks], bf1, acc[0][1], 0, 0, 0);
            acc[1][0] = __builtin_amdgcn_mfma_f32_16x16x32_f16(af[1][ks], bf0, acc[1][0], 0, 0, 0);
            acc[1][1] = __builtin_amdgcn_mfma_f32_16x16x32_f16(af[1][ks], bf1, acc[1][1], 0, 0, 0);
        }
        int h = h0 + rr;
#pragma unroll
        for (int mt = 0; mt < 2; ++mt)
#pragma unroll
            for (int nt = 0; nt < 2; ++nt) {
                int px = w0 + wv*32 + nt*16 + m16;
                int oc = g*32 + mt*16 + quad*4;
                size_t off = ((size_t)((b*128 + h)*256 + px))*128 + oc;
                float rv4[4] = {0.f, 0.f, 0.f, 0.f};
                if (RES) {
                    union { f16 h[4]; uint2 v2; } rrd;
                    rrd.v2 = *(const uint2*)(res + off);
#pragma unroll
                    for (int r = 0; r < 4; ++r) rv4[r] = (float)rrd.h[r];
                }
                union { f16 h[4]; uint2 v2; } ov;
#pragma unroll
                for (int r = 0; r < 4; ++r) {
                    float y = acc[mt][nt][r] + bo[mt][r];
                    if (LEAKY) y = y > 0.f ? y : 0.1f*y;
                    if (RES) y += rv4[r];
                    ov.h[r] = (f16)y;
                }
                *(uint2*)(out + off) = ov.v2;
            }
    }
}

// ---------------------------------------------------------------------------
// K4: grouped 1x1 conv (128->64, groups=2) + row-mean subtraction, MFMA f16.
// ---------------------------------------------------------------------------
__global__ __launch_bounds__(256, 2) void k_conv1x1m(
    const f16* __restrict__ in, const float* __restrict__ wgt,
    f16* __restrict__ outq)
{
    __shared__ f16 Xl[256][72];       // one group's 64 ic (+8 pad)
    __shared__ f16 Wl[64][72];        // all 64 oc, within-group ic
    __shared__ float partial[4][64];  // per-wave px-sums per oc
    __shared__ float meanS[64];
    int n = blockIdx.x; int t = threadIdx.x;
    int lane = t & 63, wv = t >> 6;
    int m16 = lane & 15, quad = lane >> 4;
    for (int p = t; p < 2048; p += 256) {
        int idx = p * 2; int o = idx >> 6, i = idx & 63;
        union { f16 h[2]; unsigned int u1; } pr;
        pr.h[0] = (f16)wgt[idx]; pr.h[1] = (f16)wgt[idx + 1];
        *(unsigned int*)&Wl[o][i] = pr.u1;
    }
    f32x4 acc[4][4] = {};             // [oc tile 0..3][px tile 0..3]
    const f16* rp = in + ((size_t)n*256 + t)*128;
    for (int g = 0; g < 2; ++g) {
#pragma unroll
        for (int i8 = 0; i8 < 8; ++i8)
            *(uint4*)&Xl[t][i8*8] = *(const uint4*)(rp + g*64 + i8*8);
        __syncthreads();
        half8 af[2][2], bf[4][2];
#pragma unroll
        for (int ml = 0; ml < 2; ++ml)
#pragma unroll
            for (int kk = 0; kk < 2; ++kk)
                af[ml][kk] = *(const half8*)&Wl[g*32 + ml*16 + m16][kk*32 + quad*8];
#pragma unroll
        for (int nt = 0; nt < 4; ++nt)
#pragma unroll
            for (int kk = 0; kk < 2; ++kk)
                bf[nt][kk] = *(const half8*)&Xl[wv*64 + nt*16 + m16][kk*32 + quad*8];
#pragma unroll
        for (int ml = 0; ml < 2; ++ml)
#pragma unroll
            for (int nt = 0; nt < 4; ++nt) {
                int mt = g*2 + ml;
                acc[mt][nt] = __builtin_amdgcn_mfma_f32_16x16x32_f16(af[ml][0], bf[nt][0], acc[mt][nt], 0, 0, 0);
                acc[mt][nt] = __builtin_amdgcn_mfma_f32_16x16x32_f16(af[ml][1], bf[nt][1], acc[mt][nt], 0, 0, 0);
            }
        __syncthreads();
    }
#pragma unroll
    for (int mt = 0; mt < 4; ++mt)
#pragma unroll
        for (int r = 0; r < 4; ++r) {
            float s = acc[mt][0][r] + acc[mt][1][r] + acc[mt][2][r] + acc[mt][3][r];
            s += __shfl_xor(s, 1); s += __shfl_xor(s, 2);
            s += __shfl_xor(s, 4); s += __shfl_xor(s, 8);
            if (m16 == 0) partial[wv][mt*16 + quad*4 + r] = s;
        }
    __syncthreads();
    if (t < 64)
        meanS[t] = (partial[0][t] + partial[1][t] + partial[2][t] + partial[3][t]) * (1.0f/256.0f);
    __syncthreads();
    f16* qp = outq + ((size_t)n*256)*64;
#pragma unroll
    for (int mt = 0; mt < 4; ++mt) {
        int ocb = mt*16 + quad*4;
        float m4[4]; *(float4*)m4 = *(const float4*)&meanS[ocb];
#pragma unroll
        for (int nt = 0; nt < 4; ++nt) {
            int px = wv*64 + nt*16 + m16;
            union { f16 h[4]; uint2 u2; } ov;
#pragma unroll
            for (int r = 0; r < 4; ++r)
                ov.h[r] = (f16)(acc[mt][nt][r] - m4[r]);
            *(uint2*)(qp + (size_t)px*64 + ocb) = ov.u2;
        }
    }
}

// ---------------------------------------------------------------------------
// K5: fully-fused bidirectional attention tail.  One block per n, 512 thr.
// Phase 1: S = Q·K^T -> LDS (f16 swizzled) with row AND col softmax stats
//          computed in the MFMA epilogue via shfl reductions (no serial scan).
// Then two phase-3 passes (left / right = transposed view) sharing S + stats.
// LDS: Sl 128K + pool 25.9K + stats 4K = 161.0 KiB -> 1 block/CU.
// ---------------------------------------------------------------------------

// phase-3 pass: P-chunk staging (exp), relax-window V accumulation, PV MFMA,
// tanh-blend epilogue.  RIGHT=1 reads S transposed (scalar swizzled reads).
template<int RIGHT>
__device__ __forceinline__ void attn_pass(
    const char* Sl, char* pool,
    const float* __restrict__ myM, const float* __restrict__ myI,  // by row r
    const float* __restrict__ oM,  const float* __restrict__ oI,   // by col j
    const float* __restrict__ xB, const float* __restrict__ xP,
    float* __restrict__ outp, int b, int h, int t)
{
    f16 (*Pl)[40] = (f16(*)[40])pool;               // rows +2 (window pad)
    f16 (*Xl)[40] = (f16(*)[40])(pool + 20800);
    float* scr = (float*)(pool + 20800);            // overlays Xl (post-loop)
    float* Vv  = (float*)(pool + 22848);
    int lane = t & 63, wv = t >> 6;
    int m16 = lane & 15, quad = lane >> 4;
    int W = wv * 32;
    int r = t & 255, hc = t >> 8;
    int cbase = hc * 16;
    float rm = myM[r], ri = myI[r];
    int xc = t >> 3, xj = (t & 7) * 4;
    const float* xg = xB + ((size_t)(b*64 + xc)*128 + h)*256;
    f32x4 acc[2][4] = {};
    float vacc = 0.f;
    const char* sb = Sl + (r << 9);
    int xo = (r & 7) << 4;
    for (int kc = 0; kc < 256; kc += 32) {
        float sraw[16];
        if (!RIGHT) {
            half8 v0 = *(const half8*)(sb + (((kc + cbase)*2)      ^ xo));
            half8 v1 = *(const half8*)(sb + (((kc + cbase)*2 + 16) ^ xo));
#pragma unroll
            for (int e = 0; e < 8; ++e) { sraw[e] = (float)v0[e]; sraw[8+e] = (float)v1[e]; }
        } else {
#pragma unroll
            for (int e = 0; e < 16; ++e) {
                int j = kc + cbase + e;
                sraw[e] = (float)*(const f16*)(Sl + (j << 9) + ((r*2) ^ ((j & 7) << 4)));
            }
        }
        {
            half8 p0, p1;
#pragma unroll
            for (int e = 0; e < 8; ++e) p0[e] = (f16)(__expf(sraw[e]     - rm) * ri);
#pragma unroll
            for (int e = 0; e < 8; ++e) p1[e] = (f16)(__expf(sraw[8 + e] - rm) * ri);
            char* pb = (char*)&Pl[r + 2][cbase];
            *(half8*)pb = p0; *(half8*)(pb + 16) = p1;
        }
        {
            float4 x4 = *(const float4*)(xg + kc + xj);
            union { f16 h[4]; uint2 v2; } px;
            px.h[0] = (f16)x4.x; px.h[1] = (f16)x4.y;
            px.h[2] = (f16)x4.z; px.h[3] = (f16)x4.w;
            *(uint2*)&Xl[xc][xj] = px.v2;
        }
        __syncthreads();
#pragma unroll
        for (int j8 = 0; j8 < 2; ++j8) {
            const char* wb = (const char*)&Pl[r][cbase + j8*8];
            half8 w0 = *(const half8*)(wb);
            half8 w1 = *(const half8*)(wb + 80);
            half8 w2 = *(const half8*)(wb + 160);
            half8 w3 = *(const half8*)(wb + 240);
            half8 w4 = *(const half8*)(wb + 320);
            half8 win = w0 + w1 + w2 + w3 + w4;
#pragma unroll
            for (int e = 0; e < 8; ++e) {
                int j = kc + cbase + j8*8 + e;
                float Bv = __expf(sraw[j8*8 + e] - oM[j]) * oI[j];
                vacc = fmaf((float)win[e], Bv, vacc);
            }
        }
        half8 pa[2], xb_[4];
#pragma unroll
        for (int mt = 0; mt < 2; ++mt)
            pa[mt] = *(const half8*)((const char*)&Pl[W + mt*16 + m16 + 2][0] + quad*16);
#pragma unroll
        for (int nt = 0; nt < 4; ++nt)
            xb_[nt] = *(const half8*)((const char*)&Xl[nt*16 + m16][0] + quad*16);
#pragma unroll
        for (int mt = 0; mt < 2; ++mt)
#pragma unroll
            for (int nt = 0; nt < 4; ++nt)
                acc[mt][nt] = __builtin_amdgcn_mfma_f32_16x16x32_f16(pa[mt], xb_[nt], acc[mt][nt], 0, 0, 0);
        __syncthreads();
    }
    scr[hc*256 + r] = vacc;
    __syncthreads();
    if (t < 256) Vv[t] = scr[t] + scr[256 + t];
    __syncthreads();
#pragma unroll
    for (int mt = 0; mt < 2; ++mt) {
        int i0 = W + mt*16 + quad*4;
        float v4[4];
        *(float4*)v4 = *(const float4*)&Vv[i0];
        float tv[4];
#pragma unroll
        for (int rr = 0; rr < 4; ++rr) tv[rr] = tanhf(5.f*v4[rr]);
#pragma unroll
        for (int nt = 0; nt < 4; ++nt) {
            int c = nt*16 + m16;
            size_t base = (((size_t)(b*64 + c)*128 + h) << 8) + i0;
            float xp4[4]; *(float4*)xp4 = *(const float4*)&xP[base];
            float o4[4];
#pragma unroll
            for (int rr = 0; rr < 4; ++rr)
                o4[rr] = xp4[rr]*(1.f - tv[rr]) + acc[mt][nt][rr]*tv[rr];
            *(float4*)&outp[base] = *(float4*)o4;
        }
    }
}

__global__ __launch_bounds__(512, 1) void k_attn2(
    const f16* __restrict__ Q, const f16* __restrict__ K,
    const float* __restrict__ xl, const float* __restrict__ xr,
    float* __restrict__ outL, float* __restrict__ outR)
{
    __shared__ f16 Sl[65536];          // byte = row*512 + ((col*2) ^ ((row&7)<<4))
    __shared__ __align__(16) char pool[25920];  // Pl/Xl  ∪  colM/colS ∪ scr/Vv
    __shared__ float rmS[256], riS[256], cmS[256], ciS[256];
    float* colM = (float*)pool;            // [8][256] per-wave col partial max
    float* colS = (float*)(pool + 8192);   // [8][256] per-wave col partial sum
    int n = blockIdx.x; int b = n >> 7; int h = n & 127;
    int t = threadIdx.x;
    int lane = t & 63, wv = t >> 6;
    int m16 = lane & 15, quad = lane >> 4;
    int W = wv * 32;

    // ---- phase 1: S = Q·K^T -> LDS + fused row/col stats ----
    const f16* ag = Q + (size_t)n*16384;
    const f16* bg = K + (size_t)n*16384;
    half8 af1[2][2];
#pragma unroll
    for (int mt = 0; mt < 2; ++mt)
#pragma unroll
        for (int kk = 0; kk < 2; ++kk)
            af1[mt][kk] = *(const half8*)(ag + (size_t)(W + mt*16 + m16)*64 + kk*32 + quad*8);
    float rowm[8], rows_[8];
#pragma unroll
    for (int i = 0; i < 8; ++i) { rowm[i] = -1e30f; rows_[i] = 0.f; }
    for (int jc = 0; jc < 256; jc += 64) {
        half8 bf1[4][2];
#pragma unroll
        for (int nt = 0; nt < 4; ++nt)
#pragma unroll
            for (int kk = 0; kk < 2; ++kk)
                bf1[nt][kk] = *(const half8*)(bg + (size_t)(jc + nt*16 + m16)*64 + kk*32 + quad*8);
        f32x4 acc1[2][4] = {};
#pragma unroll
        for (int mt = 0; mt < 2; ++mt)
#pragma unroll
            for (int nt = 0; nt < 4; ++nt) {
                acc1[mt][nt] = __builtin_amdgcn_mfma_f32_16x16x32_f16(af1[mt][0], bf1[nt][0], acc1[mt][nt], 0, 0, 0);
                acc1[mt][nt] = __builtin_amdgcn_mfma_f32_16x16x32_f16(af1[mt][1], bf1[nt][1], acc1[mt][nt], 0, 0, 0);
            }
        // store f16 S (swizzled) and replace acc with the f16-rounded value
#pragma unroll
        for (int mt = 0; mt < 2; ++mt)
#pragma unroll
            for (int nt = 0; nt < 4; ++nt)
#pragma unroll
                for (int r = 0; r < 4; ++r) {
                    int row = W + mt*16 + quad*4 + r;
                    int col = jc + nt*16 + m16;
                    f16 hv = (f16)acc1[mt][nt][r];
                    *(f16*)((char*)Sl + (row << 9) + ((col*2) ^ ((row & 7) << 4))) = hv;
                    acc1[mt][nt][r] = (float)hv;
                }
        // row stats: reduce over 4 in-lane cols + 16 m16-lanes, online across jc
#pragma unroll
        for (int mt = 0; mt < 2; ++mt)
#pragma unroll
            for (int r = 0; r < 4; ++r) {
                float lm = fmaxf(fmaxf(acc1[mt][0][r], acc1[mt][1][r]),
                                 fmaxf(acc1[mt][2][r], acc1[mt][3][r]));
                lm = fmaxf(lm, __shfl_xor(lm, 1));
                lm = fmaxf(lm, __shfl_xor(lm, 2));
                lm = fmaxf(lm, __shfl_xor(lm, 4));
                lm = fmaxf(lm, __shfl_xor(lm, 8));
                float le = __expf(acc1[mt][0][r] - lm) + __expf(acc1[mt][1][r] - lm)
                         + __expf(acc1[mt][2][r] - lm) + __expf(acc1[mt][3][r] - lm);
                le += __shfl_xor(le, 1); le += __shfl_xor(le, 2);
                le += __shfl_xor(le, 4); le += __shfl_xor(le, 8);
                int idx = mt*4 + r;
                float nm = fmaxf(rowm[idx], lm);
                rows_[idx] = rows_[idx]*__expf(rowm[idx] - nm) + le*__expf(lm - nm);
                rowm[idx] = nm;
            }
        // col stats: reduce over 8 in-lane rows + 4 quads -> per-wave partial
#pragma unroll
        for (int nt = 0; nt < 4; ++nt) {
            float lm = acc1[0][nt][0];
#pragma unroll
            for (int r = 1; r < 4; ++r) lm = fmaxf(lm, acc1[0][nt][r]);
#pragma unroll
            for (int r = 0; r < 4; ++r) lm = fmaxf(lm, acc1[1][nt][r]);
            lm = fmaxf(lm, __shfl_xor(lm, 16));
            lm = fmaxf(lm, __shfl_xor(lm, 32));
            float le = 0.f;
#pragma unroll
            for (int mt2 = 0; mt2 < 2; ++mt2)
#pragma unroll
                for (int r = 0; r < 4; ++r) le += __expf(acc1[mt2][nt][r] - lm);
            le += __shfl_xor(le, 16); le += __shfl_xor(le, 32);
            if (quad == 0) {
                int col = jc + nt*16 + m16;
                colM[wv*256 + col] = lm;
                colS[wv*256 + col] = le;
            }
        }
    }
    if (m16 == 0) {
#pragma unroll
        for (int mt = 0; mt < 2; ++mt)
#pragma unroll
            for (int r = 0; r < 4; ++r) {
                int row = W + mt*16 + quad*4 + r;
                rmS[row] = rowm[mt*4 + r];
                riS[row] = 1.0f / rows_[mt*4 + r];
            }
    }
    __syncthreads();
    // merge 8 per-wave col partials
    if (t < 256) {
        float m = colM[t], s = colS[t];
#pragma unroll
        for (int w = 1; w < 8; ++w) {
            float m2 = colM[w*256 + t], s2 = colS[w*256 + t];
            float nm = fmaxf(m, m2);
            s = s*__expf(m - nm) + s2*__expf(m2 - nm);
            m = nm;
        }
        cmS[t] = m; ciS[t] = 1.0f / s;
    }
    __syncthreads();
    // zero Pl window-pad rows (0,1 and 258,259) — pool now free
    if (t < 10)       *(uint4*)(pool + t*16)           = make_uint4(0,0,0,0);
    else if (t < 20)  *(uint4*)(pool + 20640 + (t-10)*16) = make_uint4(0,0,0,0);

    // ---- left pass (M_r2l rows): stats = (rm, cm); PV with x_right ----
    attn_pass<0>((const char*)Sl, pool, rmS, riS, cmS, ciS, xr, xl, outL, b, h, t);
    __syncthreads();   // protect pool reuse (Vv/Xl overlap)
    // ---- right pass (M_l2r rows = cols of S): stats swapped; PV with x_left ----
    attn_pass<1>((const char*)Sl, pool, cmS, ciS, rmS, riS, xl, xr, outR, b, h, t);
}

// ---------------------------------------------------------------------------
extern "C" void kernel_launch(void* const* d_in, const int* in_sizes, int n_in,
                              void* d_out, int out_size, void* d_ws, size_t ws_size,
                              hipStream_t stream)
{
    const float* x_left  = (const float*)d_in[0];
    const float* x_right = (const float*)d_in[1];
    const float* conv1_w = (const float*)d_in[2];
    const float* conv1_b = (const float*)d_in[3];
    const float* conv2_w = (const float*)d_in[4];
    const float* conv2_b = (const float*)d_in[5];
    const float* bn_g    = (const float*)d_in[6];
    const float* bn_b    = (const float*)d_in[7];
    const float* bn_m    = (const float*)d_in[8];
    const float* bn_v    = (const float*)d_in[9];
    const float* rb_w1   = (const float*)d_in[10];
    const float* rb_b1   = (const float*)d_in[11];
    const float* rb_w2   = (const float*)d_in[12];
    const float* rb_b2   = (const float*)d_in[13];
    const float* bq_w    = (const float*)d_in[14];
    const float* bs_w    = (const float*)d_in[16];

    f16* W16 = (f16*)d_ws;
    f16* u  = W16;                       // 16,777,216 els
    f16* y1 = W16 + 16777216;            // 16,777,216
    f16* r  = W16 + 33554432;            // 16,777,216
    f16* Qh = W16 + 67108864;            //  8,388,608
    f16* Kh = W16 + 75497472;            //  8,388,608
    f16* Wp1 = W16 + 84934656;           // 36,864 els (prepped rb_w1)
    f16* Wp2 = W16 + 84971520;           // 36,864 els (prepped rb_w2)

    float* out_left  = (float*)d_out;
    float* out_right = (float*)d_out + 8388608;

    // ---- weight prep (once per launch) ----
    k_wprep<<<dim3(4, 2), 256, 0, stream>>>(rb_w1, rb_w2, Wp1, Wp2);

    // ---- left branch -> Q ----
    k_catbn_m<<<NN, 256, 0, stream>>>(x_left, conv1_w, conv1_b, bn_g, bn_b, bn_m, bn_v, u);
    k_conv3r<true,  false><<<dim3(128, 4, 2), 256, 0, stream>>>(u, Wp1, rb_b1, nullptr, y1);
    k_conv3r<false, true ><<<dim3(128, 4, 2), 256, 0, stream>>>(y1, Wp2, rb_b2, u, r);
    k_conv1x1m<<<NN, 256, 0, stream>>>(r, bq_w, Qh);

    // ---- right branch -> K ----
    k_catbn_m<<<NN, 256, 0, stream>>>(x_right, conv2_w, conv2_b, bn_g, bn_b, bn_m, bn_v, u);
    k_conv3r<true,  false><<<dim3(128, 4, 2), 256, 0, stream>>>(u, Wp1, rb_b1, nullptr, y1);
    k_conv3r<false, true ><<<dim3(128, 4, 2), 256, 0, stream>>>(y1, Wp2, rb_b2, u, r);
    k_conv1x1m<<<NN, 256, 0, stream>>>(r, bs_w, Kh);

    // ---- fused bidirectional attention tail (single launch) ----
    k_attn2<<<NN, 512, 0, stream>>>(Qh, Kh, x_left, x_right, out_left, out_right);
}